// Round 4
// baseline (175.517 us; speedup 1.0000x reference)
//
#include <hip/hip_runtime.h>

// N = 8,388,608 rows, C = 3 classes (fp32 log-probs), int32 labels.
// out = -sum_i( w_i * pre[i, y_i] ) / N, w_i = (|argmax(pre_i) - y_i| == 2) ? weight : 1
//
// Memory-bound: 96 MiB pre + 32 MiB labels -> ~21 us @ 6.3 TB/s ideal.
// History (kernel-only time; total dur_us carries ~124 us of harness poison fills):
//   R0 one-shot strided 48B loads:            ~49 us
//   R1 one-shot coalesced + __syncthreads:     63.5 us (occupancy 38% -> CU starvation)
//   R2 one-shot coalesced + wave-private LDS:  ~50 us
// All three cap at ~2.1-2.7 TB/s regardless of addressing -> the shared limiter is
// BLOCK CHURN: one-shot blocks issue a burst, drain, exit; the VMEM queue empties
// between block waves (Little's law: only ~1.3 MB in flight at 2.6 TB/s).
//
// R3 (this): persistent pipelined grid. 1024 blocks (4/CU at 24.6 KiB LDS, all
// co-resident, 16 waves/CU). Each wave loops 8 chunks of 256 contiguous rows with
// 2-deep register prefetch: stage chunk k to wave-private LDS slice, issue chunk
// k+2's loads into the freed registers, wave-local lgkmcnt(0), compute. No
// s_barrier in the memory stream; the load queue never drains.
//
// Single kernel, no zero pass: d_out poison 0xAAAAAAAA == -3.03e-13f is
// negligible vs result ~1.3 and threshold 3.58e-2 -> atomicAdd onto it.

#define N_ROWS   8388608
#define BLOCK    256
#define GRID     1024
#define WPB      (BLOCK / 64)                  // 4 waves/block
#define NWAVES   (GRID * WPB)                  // 4096
#define CHUNK    256                           // rows per wave-iteration
#define NITER    (N_ROWS / (NWAVES * CHUNK))   // 8
#define ROWS_PW  (CHUNK * NITER)               // 2048 contiguous rows per wave

__global__ __launch_bounds__(BLOCK) void nll_fused_kernel(
        const float* __restrict__ pre,
        const int*   __restrict__ y_true,
        const float* __restrict__ wptr,
        float*       __restrict__ out) {
    __shared__ float tile[WPB][2][768];  // per-wave double-buffered 3 KiB slices
    __shared__ float red[WPB];

    const float wgt  = wptr[0];
    const int   t    = threadIdx.x;
    const int   lane = t & 63;
    const int   wv   = t >> 6;
    const int   W    = (int)blockIdx.x * WPB + wv;   // global wave id, [0, 4096)

    const float4* __restrict__ pre4 = (const float4*)pre;

    const int fbW = W * (ROWS_PW * 3 / 4);   // float4 base for this wave (max ~6.29M)
    const int ybW = W * ROWS_PW;             // row base for this wave

    // 2-deep pipeline registers: 24 VGPR (pre) + 8 VGPR (labels)
    float4 v[2][3];
    int    yv[2][4];

    // ---- prologue: chunks 0 and 1 in flight (14 loads, all coalesced) ------
    #pragma unroll
    for (int p = 0; p < 2; ++p) {
        const int fb = fbW + p * 192;
        const int yb = ybW + p * 256;
        v[p][0] = pre4[fb +       lane];
        v[p][1] = pre4[fb +  64 + lane];
        v[p][2] = pre4[fb + 128 + lane];
        yv[p][0] = y_true[yb +       lane];
        yv[p][1] = y_true[yb +  64 + lane];
        yv[p][2] = y_true[yb + 128 + lane];
        yv[p][3] = y_true[yb + 192 + lane];
    }

    float acc = 0.0f;
    #pragma unroll
    for (int k = 0; k < NITER; ++k) {        // fully unrolled: all indices static
        const int b = k & 1;
        float*  slice = tile[wv][b];
        float4* s4    = (float4*)slice;

        // Stage chunk k (compiler inserts a PARTIAL vmcnt for chunk k's loads;
        // chunk k+1's stay in flight). Linear b128 writes: conflict-free.
        s4[       lane] = v[b][0];
        s4[ 64 +  lane] = v[b][1];
        s4[128 +  lane] = v[b][2];

        // Save labels before the prefetch overwrites yv[b].
        const int y0 = yv[b][0], y1 = yv[b][1], y2 = yv[b][2], y3 = yv[b][3];

        // Prefetch chunk k+2 into the register set just consumed: the queue
        // always holds ~2 chunks (14 loads) per wave x 16 waves/CU.
        if (k + 2 < NITER) {
            const int fb = fbW + (k + 2) * 192;
            const int yb = ybW + (k + 2) * 256;
            v[b][0] = pre4[fb +       lane];
            v[b][1] = pre4[fb +  64 + lane];
            v[b][2] = pre4[fb + 128 + lane];
            yv[b][0] = y_true[yb +       lane];
            yv[b][1] = y_true[yb +  64 + lane];
            yv[b][2] = y_true[yb + 128 + lane];
            yv[b][3] = y_true[yb + 192 + lane];
        }

        // Drain only THIS wave's DS ops. Same-wave producer/consumer: no
        // s_barrier. "memory" clobber keeps the ds_reads below from hoisting.
        asm volatile("s_waitcnt lgkmcnt(0)" ::: "memory");

        const int yls[4] = {y0, y1, y2, y3};
        #pragma unroll
        for (int m = 0; m < 4; ++m) {
            // Row r = chunkbase + lane + 64m: LDS word 3*lane+192m -> stride-3
            // across lanes, gcd(3,32)=1 -> 2 lanes/bank (free on CDNA4).
            const int   w0 = 3 * lane + 192 * m;
            const float p0 = slice[w0 + 0];
            const float p1 = slice[w0 + 1];
            const float p2 = slice[w0 + 2];
            const int   tt = yls[m];
            const float picked = (tt == 0) ? p0 : ((tt == 1) ? p1 : p2);
            // first-occurrence argmax over 3 (matches jnp.argmax tie-break)
            int   prd = 0;
            float mx  = p0;
            if (p1 > mx) { mx = p1; prd = 1; }
            if (p2 > mx) { prd = 2; }
            const bool penal = (prd - tt == 2) || (tt - prd == 2);
            acc += (penal ? wgt : 1.0f) * picked;
        }
        // WAR (reads of slice[b] at iter k vs writes at iter k+2) is separated
        // by iter k+1's lgkmcnt(0): safe.
    }

    // ---- reduction: wave shuffle, then one tiny block combine --------------
    #pragma unroll
    for (int off = 32; off > 0; off >>= 1)
        acc += __shfl_down(acc, off, 64);

    if (lane == 0) red[wv] = acc;
    __syncthreads();                       // after ALL memory work: harmless

    if (t == 0) {
        const float s = red[0] + red[1] + red[2] + red[3];
        // out was memset(0) (correctness call) or poisoned to 0xAA
        // (== -3.03e-13f) before each timed replay; negligible bias.
        atomicAdd(out, s * (-1.0f / (float)N_ROWS));
    }
}

extern "C" void kernel_launch(void* const* d_in, const int* in_sizes, int n_in,
                              void* d_out, int out_size, void* d_ws, size_t ws_size,
                              hipStream_t stream) {
    const float* pre  = (const float*)d_in[0];
    const int*   y    = (const int*)d_in[1];
    const float* wptr = (const float*)d_in[2];
    float* out = (float*)d_out;

    nll_fused_kernel<<<GRID, BLOCK, 0, stream>>>(pre, y, wptr, out);
}

// Round 8
// 159.752 us; speedup vs baseline: 1.0987x; 1.0987x over previous
//
#include <hip/hip_runtime.h>

// N = 8,388,608 rows, C = 3 classes (fp32 log-probs), int32 labels.
// out = -sum_i( w_i * pre[i, y_i] ) / N, w_i = (|argmax(pre_i) - y_i| == 2) ? weight : 1
//
// History (kernel-only; total dur_us carries ~123 us of harness poison fills):
//   R0 one-shot strided:                 ~49 us
//   R1 one-shot coalesced + barrier:      63.5 us
//   R2 one-shot coalesced, wave-private:  ~50 us
//   R3 persistent pipelined (this-1):     ~52 us
// All cap at 2.1-2.7 TB/s pure READ while the harness fills do 6.9 TB/s pure
// WRITE on the same chip. Churn/occupancy/coalescing theories all dead.
// Remaining suspects, both attacked here:
//  (a) cache-allocation overhead on the read path -> NT loads (bypass L2/L3
//      allocation; FETCH_SIZE must rise 67 MB -> ~134 MB, proving they land)
//  (b) same-address atomicAdd tail (1024 RMWs to ONE address, cross-XCD line
//      bouncing) -> removed: per-block partials to d_ws + tiny reduce kernel.
// Pipeline deepened to 3 register buffers: prefetch of chunk k+2 issues BEFORE
// the LDS write that forces the vmcnt wait on chunk k, so 2 full chunks are in
// flight during every wait.

typedef float v4f __attribute__((ext_vector_type(4)));

#define N_ROWS   8388608
#define BLOCK    256
#define GRID     1024
#define WPB      (BLOCK / 64)                  // 4 waves/block
#define NWAVES   (GRID * WPB)                  // 4096
#define CHUNK    256                           // rows per wave-iteration
#define NITER    (N_ROWS / (NWAVES * CHUNK))   // 8
#define ROWS_PW  (CHUNK * NITER)               // 2048 contiguous rows per wave

__global__ __launch_bounds__(BLOCK) void nll_main(
        const float* __restrict__ pre,
        const int*   __restrict__ y_true,
        const float* __restrict__ wptr,
        float*       __restrict__ partial) {
    __shared__ float tile[WPB][2][768];  // per-wave double-buffered 3 KiB slices
    __shared__ float red[WPB];

    const float wgt  = wptr[0];
    const int   t    = threadIdx.x;
    const int   lane = t & 63;
    const int   wv   = t >> 6;
    const int   W    = (int)blockIdx.x * WPB + wv;   // global wave id [0, 4096)

    const v4f* __restrict__ pre4 = (const v4f*)pre;
    const int fbW = W * (ROWS_PW * 3 / 4);   // float4 base (max ~6.29M, fits int)
    const int ybW = W * ROWS_PW;             // row base

    // 3-deep pipeline registers (36 + 12 VGPR)
    v4f v[3][3];
    int yv[3][4];

    // ---- prologue: chunks 0 and 1 in flight (14 NT loads, all coalesced) ---
    #pragma unroll
    for (int p = 0; p < 2; ++p) {
        const int fb = fbW + p * 192;
        const int yb = ybW + p * 256;
        v[p][0] = __builtin_nontemporal_load(pre4 + fb +       lane);
        v[p][1] = __builtin_nontemporal_load(pre4 + fb +  64 + lane);
        v[p][2] = __builtin_nontemporal_load(pre4 + fb + 128 + lane);
        yv[p][0] = __builtin_nontemporal_load(y_true + yb +       lane);
        yv[p][1] = __builtin_nontemporal_load(y_true + yb +  64 + lane);
        yv[p][2] = __builtin_nontemporal_load(y_true + yb + 128 + lane);
        yv[p][3] = __builtin_nontemporal_load(y_true + yb + 192 + lane);
    }

    float acc = 0.0f;
    #pragma unroll
    for (int k = 0; k < NITER; ++k) {        // fully unrolled: all indices static
        const int b  = k % 3;                // buffer being consumed
        const int nb = (k + 2) % 3;          // buffer being refilled (b+2 mod 3 != b)

        // Prefetch chunk k+2 FIRST: issued before the vmcnt-forcing LDS write,
        // so chunks k+1 and k+2 (14 loads, ~7 KB/wave) stay in flight while we
        // wait for chunk k. Per CU: 16 waves x 7 KB ~ 112 KB outstanding.
        if (k + 2 < NITER) {
            const int fb = fbW + (k + 2) * 192;
            const int yb = ybW + (k + 2) * 256;
            v[nb][0] = __builtin_nontemporal_load(pre4 + fb +       lane);
            v[nb][1] = __builtin_nontemporal_load(pre4 + fb +  64 + lane);
            v[nb][2] = __builtin_nontemporal_load(pre4 + fb + 128 + lane);
            yv[nb][0] = __builtin_nontemporal_load(y_true + yb +       lane);
            yv[nb][1] = __builtin_nontemporal_load(y_true + yb +  64 + lane);
            yv[nb][2] = __builtin_nontemporal_load(y_true + yb + 128 + lane);
            yv[nb][3] = __builtin_nontemporal_load(y_true + yb + 192 + lane);
        }

        // Stage chunk k to this wave's private slice (compiler inserts the
        // partial vmcnt for chunk k only). Linear b128 writes: conflict-free.
        float* slice = tile[wv][k & 1];
        v4f*   s4    = (v4f*)slice;
        s4[       lane] = v[b][0];
        s4[ 64 +  lane] = v[b][1];
        s4[128 +  lane] = v[b][2];

        // Drain only THIS wave's DS ops; no s_barrier anywhere in the stream.
        asm volatile("s_waitcnt lgkmcnt(0)" ::: "memory");

        #pragma unroll
        for (int m = 0; m < 4; ++m) {
            // Row r = chunkbase + lane + 64m -> LDS word 3*lane+192m: stride-3
            // across lanes, gcd(3,32)=1 -> 2 lanes/bank (free on CDNA4).
            const int   w0 = 3 * lane + 192 * m;
            const float p0 = slice[w0 + 0];
            const float p1 = slice[w0 + 1];
            const float p2 = slice[w0 + 2];
            const int   tt = yv[b][m];
            const float picked = (tt == 0) ? p0 : ((tt == 1) ? p1 : p2);
            // first-occurrence argmax over 3 (matches jnp.argmax tie-break)
            int   prd = 0;
            float mx  = p0;
            if (p1 > mx) { mx = p1; prd = 1; }
            if (p2 > mx) { prd = 2; }
            const bool penal = (prd - tt == 2) || (tt - prd == 2);
            acc += (penal ? wgt : 1.0f) * picked;
        }
        // WAR (reads of slice[k&1] at iter k vs writes at iter k+2) is
        // separated by iter k+1's lgkmcnt(0): safe.
    }

    // ---- block partial: wave shuffle + tiny LDS combine, NO atomics --------
    #pragma unroll
    for (int off = 32; off > 0; off >>= 1)
        acc += __shfl_down(acc, off, 64);

    if (lane == 0) red[wv] = acc;
    __syncthreads();                       // after ALL memory work: harmless

    if (t == 0)
        partial[blockIdx.x] = red[0] + red[1] + red[2] + red[3];
}

// Second launch on the same stream (graph-legal): reduce 1024 partials.
// Plain store to out -> no reliance on poison-negligibility anymore.
__global__ __launch_bounds__(256) void nll_reduce(
        const float* __restrict__ partial,
        float*       __restrict__ out) {
    const float4 p = ((const float4*)partial)[threadIdx.x];   // 256*4 = 1024
    float s = p.x + p.y + p.z + p.w;
    #pragma unroll
    for (int off = 32; off > 0; off >>= 1)
        s += __shfl_down(s, off, 64);

    __shared__ float r[4];
    if ((threadIdx.x & 63) == 0) r[threadIdx.x >> 6] = s;
    __syncthreads();
    if (threadIdx.x == 0)
        out[0] = (r[0] + r[1] + r[2] + r[3]) * (-1.0f / (float)N_ROWS);
}

extern "C" void kernel_launch(void* const* d_in, const int* in_sizes, int n_in,
                              void* d_out, int out_size, void* d_ws, size_t ws_size,
                              hipStream_t stream) {
    const float* pre  = (const float*)d_in[0];
    const int*   y    = (const int*)d_in[1];
    const float* wptr = (const float*)d_in[2];
    float* ws  = (float*)d_ws;       // 4 KiB of workspace for 1024 partials
    float* out = (float*)d_out;

    nll_main<<<GRID, BLOCK, 0, stream>>>(pre, y, wptr, ws);
    nll_reduce<<<1, 256, 0, stream>>>(ws, out);
}